// Round 2
// baseline (472.756 us; speedup 1.0000x reference)
//
#include <hip/hip_runtime.h>

// MultiHeadAttention: B=2, S=2048, D_MODEL=1024, H=16, depth=64.
// I/O is FP32 (per reference); compute is bf16 MFMA with fp32 accumulate.
// Pipeline: q/k/v projections (BT-GEMM, fp32->bf16) -> flash attention (bf16)
//           -> output projection (bf16 A, fp32 W, fp32 out).
// Workspace (bf16): qh(8MB) kh(8MB) vt(8MB) at(8MB) = 32MB.

typedef unsigned short u16;
typedef __attribute__((ext_vector_type(8))) __bf16 bf16x8;   // MFMA A/B fragment
typedef __attribute__((ext_vector_type(8))) u16    u16x8;    // 16B bf16-store type
typedef __attribute__((ext_vector_type(8))) short  short8;   // raw 16B copy type
typedef __attribute__((ext_vector_type(4))) float  f32x4;    // MFMA C/D + float4 loads

#define MFMA16(a, b, c) __builtin_amdgcn_mfma_f32_16x16x32_bf16((a), (b), (c), 0, 0, 0)

__device__ __forceinline__ u16 f2bf(float f) {           // RNE float->bf16 (finite inputs)
    unsigned int u = __float_as_uint(f);
    return (u16)((u + 0x7FFF + ((u >> 16) & 1)) >> 16);
}

// ---------------------------------------------------------------------------
// BT-GEMM: C[m,n] = sum_k A[m,k] * W[n,k] + bias[n];  M=4096, N=1024, K=1024.
// 128x128 tile, BK=32, 256 threads (4 waves 2x2, each wave 64x64 = 4x4 MFMA tiles).
// AF32: A is fp32 (convert while staging) else bf16-in-ws raw copy.
// LAYOUT: 0 -> (B,H,S,64); 1 -> (B,H,64,S); 2 -> (M,N) row-major.
// OUTF32: write fp32 (d_out) else bf16 u16 (ws).
// ---------------------------------------------------------------------------
template<int AF32, int LAYOUT, int OUTF32>
__global__ __launch_bounds__(256, 2)
void gemm_bt(const void* __restrict__ Av, const float* __restrict__ W,
             const float* __restrict__ bias, void* __restrict__ outv)
{
    __shared__ __align__(16) u16 As[128 * 32];
    __shared__ __align__(16) u16 Bs[128 * 32];
    const int tid  = threadIdx.x;
    const int wave = tid >> 6, lane = tid & 63;
    const int quad = lane >> 4, l16 = lane & 15;
    const int wr = (wave >> 1) * 64, wc = (wave & 1) * 64;
    const int m0 = blockIdx.y * 128, n0 = blockIdx.x * 128;

    f32x4 acc[4][4] = {};

    for (int k0 = 0; k0 < 1024; k0 += 32) {
        __syncthreads();
        #pragma unroll
        for (int it = 0; it < 2; it++) {
            int idx = it * 256 + tid;            // 512 16B-chunks per 128x32 tile
            int row = idx >> 2, col = (idx & 3) * 8;
            // A tile
            if (AF32) {
                const float* src = (const float*)Av + (size_t)(m0 + row) * 1024 + k0 + col;
                f32x4 lo = *(const f32x4*)src, hi = *(const f32x4*)(src + 4);
                u16x8 v;
                #pragma unroll
                for (int t = 0; t < 4; t++) { v[t] = f2bf(lo[t]); v[4 + t] = f2bf(hi[t]); }
                *(u16x8*)(As + row * 32 + col) = v;
            } else {
                *(short8*)(As + row * 32 + col) =
                    *(const short8*)((const u16*)Av + (size_t)(m0 + row) * 1024 + k0 + col);
            }
            // W tile (always fp32 input)
            {
                const float* src = W + (size_t)(n0 + row) * 1024 + k0 + col;
                f32x4 lo = *(const f32x4*)src, hi = *(const f32x4*)(src + 4);
                u16x8 v;
                #pragma unroll
                for (int t = 0; t < 4; t++) { v[t] = f2bf(lo[t]); v[4 + t] = f2bf(hi[t]); }
                *(u16x8*)(Bs + row * 32 + col) = v;
            }
        }
        __syncthreads();
        bf16x8 af[4], bfr[4];
        #pragma unroll
        for (int i = 0; i < 4; i++)
            af[i] = *(const bf16x8*)(As + (wr + i * 16 + l16) * 32 + quad * 8);
        #pragma unroll
        for (int j = 0; j < 4; j++)
            bfr[j] = *(const bf16x8*)(Bs + (wc + j * 16 + l16) * 32 + quad * 8);
        #pragma unroll
        for (int i = 0; i < 4; i++)
            #pragma unroll
            for (int j = 0; j < 4; j++)
                acc[i][j] = MFMA16(af[i], bfr[j], acc[i][j]);
    }

    float bv[4];
    #pragma unroll
    for (int j = 0; j < 4; j++) bv[j] = bias[n0 + wc + j * 16 + l16];

    // C/D layout: col = lane&15 (n), row = quad*4 + reg (m)
    #pragma unroll
    for (int i = 0; i < 4; i++) {
        #pragma unroll
        for (int j = 0; j < 4; j++) {
            int gn = n0 + wc + j * 16 + l16;
            #pragma unroll
            for (int r = 0; r < 4; r++) {
                int gm = m0 + wr + i * 16 + quad * 4 + r;
                float v = acc[i][j][r] + bv[j];
                size_t idx;
                if (LAYOUT == 2)      idx = (size_t)gm * 1024 + gn;
                else if (LAYOUT == 0) idx = (((size_t)(gm >> 11) * 16 + (gn >> 6)) * 2048 + (gm & 2047)) * 64 + (gn & 63);
                else                  idx = (((size_t)(gm >> 11) * 16 + (gn >> 6)) * 64 + (gn & 63)) * 2048 + (gm & 2047);
                if (OUTF32) ((float*)outv)[idx] = v;
                else        ((u16*)outv)[idx]   = f2bf(v);
            }
        }
    }
}

// ---------------------------------------------------------------------------
// Flash attention: one block per (q-tile of 128, head, batch). 4 waves x 32 q-rows.
// qh/kh: (B,H,S,64) bf16; vt: (B,H,64,S) bf16; at out: (B,S,1024) bf16 row-major.
// ---------------------------------------------------------------------------
__global__ __launch_bounds__(256, 2)
void attn_fused(const u16* __restrict__ qh, const u16* __restrict__ kh,
                const u16* __restrict__ vt, u16* __restrict__ out)
{
    __shared__ __align__(16) u16 Ks[128 * 64];      // kv-rows x depth      (16KB)
    __shared__ __align__(16) u16 Vs[64 * 128];      // depth-rows x kv      (16KB)
    __shared__ __align__(16) u16 Ps[4 * 32 * 128];  // per-wave P scratch   (32KB)

    const int tid  = threadIdx.x;
    const int wave = tid >> 6, lane = tid & 63;
    const int quad = lane >> 4, l16 = lane & 15;
    const int q0 = blockIdx.x * 128;
    const int h = blockIdx.y, b = blockIdx.z;

    const size_t head = (size_t)(b * 16 + h);
    const u16* qh_h = qh + head * (2048 * 64);
    const u16* kh_h = kh + head * (2048 * 64);
    const u16* vt_h = vt + head * (64 * 2048);
    u16* pw = Ps + wave * (32 * 128);

    // Q fragments held in registers (A-op: m=lane&15, k=quad*8+j)
    bf16x8 qf[2][2];
    #pragma unroll
    for (int i = 0; i < 2; i++)
        #pragma unroll
        for (int ks = 0; ks < 2; ks++)
            qf[i][ks] = *(const bf16x8*)(qh_h + (size_t)(q0 + wave * 32 + i * 16 + l16) * 64 + ks * 32 + quad * 8);

    f32x4 oacc[2][4] = {};
    float m_s[2][4], l_s[2][4];
    #pragma unroll
    for (int i = 0; i < 2; i++)
        #pragma unroll
        for (int r = 0; r < 4; r++) { m_s[i][r] = -1e30f; l_s[i][r] = 0.0f; }

    const float c = 0.18033688011112042f;  // log2(e) / sqrt(64)

    for (int kt = 0; kt < 16; kt++) {
        const int kv0 = kt * 128;
        __syncthreads();  // protect Ks/Vs/Ps from previous iteration's readers
        #pragma unroll
        for (int it = 0; it < 4; it++) {
            int idx = it * 256 + tid;
            ((short8*)Ks)[idx] = ((const short8*)(kh_h + (size_t)kv0 * 64))[idx];  // 16KB contiguous
            int row = idx >> 4, col = (idx & 15) * 8;
            ((short8*)Vs)[idx] = *(const short8*)(vt_h + (size_t)row * 2048 + kv0 + col);
        }
        __syncthreads();

        // S = q . k^T (raw scores; 1/8 folded into exponent scale)
        f32x4 sacc[2][8] = {};
        #pragma unroll
        for (int j = 0; j < 8; j++) {
            #pragma unroll
            for (int ks = 0; ks < 2; ks++) {
                bf16x8 kf = *(const bf16x8*)(Ks + (j * 16 + l16) * 64 + ks * 32 + quad * 8);
                #pragma unroll
                for (int i = 0; i < 2; i++)
                    sacc[i][j] = MFMA16(qf[i][ks], kf, sacc[i][j]);
            }
        }

        // Online softmax. Row (i*16 + quad*4 + rg) lives in one 16-lane group.
        #pragma unroll
        for (int i = 0; i < 2; i++) {
            #pragma unroll
            for (int rg = 0; rg < 4; rg++) {
                float mx = sacc[i][0][rg];
                #pragma unroll
                for (int j = 1; j < 8; j++) mx = fmaxf(mx, sacc[i][j][rg]);
                #pragma unroll
                for (int off = 8; off > 0; off >>= 1) mx = fmaxf(mx, __shfl_xor(mx, off));
                float mnew  = fmaxf(m_s[i][rg], mx);
                float alpha = __builtin_amdgcn_exp2f((m_s[i][rg] - mnew) * c);
                m_s[i][rg]  = mnew;
                float rs = 0.0f;
                #pragma unroll
                for (int j = 0; j < 8; j++) {
                    float p = __builtin_amdgcn_exp2f((sacc[i][j][rg] - mnew) * c);
                    rs += p;
                    pw[(i * 16 + quad * 4 + rg) * 128 + j * 16 + l16] = f2bf(p);
                }
                #pragma unroll
                for (int off = 8; off > 0; off >>= 1) rs += __shfl_xor(rs, off);
                l_s[i][rg] = l_s[i][rg] * alpha + rs;
                #pragma unroll
                for (int dt = 0; dt < 4; dt++) oacc[i][dt][rg] *= alpha;
            }
        }
        __syncthreads();  // P writes visible before re-reading as MFMA A-operand

        // O += P * V   (P from LDS as A-op; Vs rows are depth, kv-contiguous)
        #pragma unroll
        for (int ks = 0; ks < 4; ks++) {
            #pragma unroll
            for (int i = 0; i < 2; i++) {
                bf16x8 pa = *(const bf16x8*)(pw + (i * 16 + l16) * 128 + ks * 32 + quad * 8);
                #pragma unroll
                for (int dt = 0; dt < 4; dt++) {
                    bf16x8 vf = *(const bf16x8*)(Vs + (dt * 16 + l16) * 128 + ks * 32 + quad * 8);
                    oacc[i][dt] = MFMA16(pa, vf, oacc[i][dt]);
                }
            }
        }
    }

    #pragma unroll
    for (int i = 0; i < 2; i++) {
        #pragma unroll
        for (int rg = 0; rg < 4; rg++) {
            float inv = 1.0f / l_s[i][rg];
            int gq = q0 + wave * 32 + i * 16 + quad * 4 + rg;
            #pragma unroll
            for (int dt = 0; dt < 4; dt++) {
                int col = h * 64 + dt * 16 + l16;
                out[((size_t)(b * 2048 + gq)) * 1024 + col] = f2bf(oacc[i][dt][rg] * inv);
            }
        }
    }
}

extern "C" void kernel_launch(void* const* d_in, const int* in_sizes, int n_in,
                              void* d_out, int out_size, void* d_ws, size_t ws_size,
                              hipStream_t stream)
{
    const void*  Q   = d_in[0];
    const void*  Kin = d_in[1];
    const void*  V   = d_in[2];
    const float* Wq  = (const float*)d_in[3];
    const float* bq  = (const float*)d_in[4];
    const float* Wk  = (const float*)d_in[5];
    const float* bk  = (const float*)d_in[6];
    const float* Wv  = (const float*)d_in[7];
    const float* bv  = (const float*)d_in[8];
    const float* Wo  = (const float*)d_in[9];
    const float* bo  = (const float*)d_in[10];

    const size_t SZ = (size_t)2 * 2048 * 1024;  // elements per bf16 ws buffer (8MB)
    u16* qh = (u16*)d_ws;
    u16* kh = qh + SZ;
    u16* vt = kh + SZ;
    u16* at = vt + SZ;

    dim3 gg(8, 32), blk(256);
    gemm_bt<1, 0, 0><<<gg, blk, 0, stream>>>(Q,   Wq, bq, qh);
    gemm_bt<1, 0, 0><<<gg, blk, 0, stream>>>(Kin, Wk, bk, kh);
    gemm_bt<1, 1, 0><<<gg, blk, 0, stream>>>(V,   Wv, bv, vt);
    attn_fused<<<dim3(16, 16, 2), blk, 0, stream>>>(qh, kh, vt, at);
    gemm_bt<0, 2, 1><<<gg, blk, 0, stream>>>(at,  Wo, bo, d_out);
}

// Round 3
// 272.255 us; speedup vs baseline: 1.7364x; 1.7364x over previous
//
#include <hip/hip_runtime.h>

// MultiHeadAttention: B=2, S=2048, D_MODEL=1024, H=16, depth=64. FP32 I/O.
// Phases: (1) convert Q/K/V + weights fp32->bf16, (2) fused QKV projection
// (m97-style global_load_lds GEMM), (3) flash attention (padded LDS),
// (4) O-projection (fp32 out).
// ws (bf16): Qb Kb Vb qh kh vt (6 x 8.39MB) + Wqb Wkb Wvb Wob (4 x 2.1MB); at aliases Qb.

typedef unsigned short u16;
typedef __attribute__((ext_vector_type(8))) __bf16 bf16x8;   // MFMA A/B fragment
typedef __attribute__((ext_vector_type(8))) u16    u16x8;
typedef __attribute__((ext_vector_type(8))) short  short8;
typedef __attribute__((ext_vector_type(4))) float  f32x4;    // MFMA C/D

#define MFMA16(a, b, c) __builtin_amdgcn_mfma_f32_16x16x32_bf16((a), (b), (c), 0, 0, 0)

__device__ __forceinline__ u16 f2bf(float f) {               // RNE float->bf16
    unsigned int u = __float_as_uint(f);
    return (u16)((u + 0x7FFF + ((u >> 16) & 1)) >> 16);
}

__device__ __forceinline__ void gl2lds16(const void* g, void* l) {  // async 16B global->LDS
    __builtin_amdgcn_global_load_lds((const __attribute__((address_space(1))) unsigned int*)g,
                                     (__attribute__((address_space(3))) unsigned int*)l, 16, 0, 0);
}

// ---------------------------------------------------------------------------
// fp32 -> bf16 converts
// ---------------------------------------------------------------------------
__global__ __launch_bounds__(256)
void cvt_qkv(const float* __restrict__ Q, const float* __restrict__ K, const float* __restrict__ V,
             u16* __restrict__ oq, u16* __restrict__ ok, u16* __restrict__ ov)
{
    const int z = blockIdx.y;
    const float* s = z == 0 ? Q : (z == 1 ? K : V);
    u16* d = z == 0 ? oq : (z == 1 ? ok : ov);
    size_t i = ((size_t)blockIdx.x * 256 + threadIdx.x) * 8;
    f32x4 lo = *(const f32x4*)(s + i), hi = *(const f32x4*)(s + i + 4);
    u16x8 v;
    #pragma unroll
    for (int t = 0; t < 4; t++) { v[t] = f2bf(lo[t]); v[4 + t] = f2bf(hi[t]); }
    *(u16x8*)(d + i) = v;
}

__global__ __launch_bounds__(256)
void cvt_w(const float* __restrict__ W0, const float* __restrict__ W1,
           const float* __restrict__ W2, const float* __restrict__ W3,
           u16* __restrict__ o0, u16* __restrict__ o1, u16* __restrict__ o2, u16* __restrict__ o3)
{
    const int z = blockIdx.y;
    const float* s = z == 0 ? W0 : (z == 1 ? W1 : (z == 2 ? W2 : W3));
    u16* d = z == 0 ? o0 : (z == 1 ? o1 : (z == 2 ? o2 : o3));
    size_t i = ((size_t)blockIdx.x * 256 + threadIdx.x) * 8;
    f32x4 lo = *(const f32x4*)(s + i), hi = *(const f32x4*)(s + i + 4);
    u16x8 v;
    #pragma unroll
    for (int t = 0; t < 4; t++) { v[t] = f2bf(lo[t]); v[4 + t] = f2bf(hi[t]); }
    *(u16x8*)(d + i) = v;
}

// ---------------------------------------------------------------------------
// m97-style BT-GEMM body: C[m,n] = sum_k A[m,k]*W[n,k] + bias[n]; M=4096 N=1024 K=1024.
// 128x128 tile, BK=32, 256 thr (4 waves 2x2, 64x64/wave). global_load_lds width-16.
// LAYOUT: 0 -> (B,H,S,64); 1 -> (B,H,64,S); 2 -> (M,N) row-major. OUTF32: fp32 store.
// ---------------------------------------------------------------------------
template<int LAYOUT, int OUTF32>
__device__ __forceinline__ void gemm_body(const u16* __restrict__ A, const u16* __restrict__ W,
                                          const float* __restrict__ bias, void* __restrict__ outv,
                                          u16* As, u16* Bs)
{
    const int tid  = threadIdx.x;
    const int wave = tid >> 6, lane = tid & 63;
    const int quad = lane >> 4, l16 = lane & 15;
    const int wr = (wave >> 1) * 64, wc = (wave & 1) * 64;
    const int m0 = blockIdx.y * 128, n0 = blockIdx.x * 128;

    f32x4 acc[4][4] = {};

    for (int k0 = 0; k0 < 1024; k0 += 32) {
        __syncthreads();
        #pragma unroll
        for (int t = 0; t < 2; t++) {
            int idx = t * 256 + tid;                    // 512 16B chunks per 128x32 tile
            int row = idx >> 2, col = (idx & 3) * 8;
            gl2lds16(A + (size_t)(m0 + row) * 1024 + k0 + col, As + idx * 8);
            gl2lds16(W + (size_t)(n0 + row) * 1024 + k0 + col, Bs + idx * 8);
        }
        __syncthreads();                                // drains vmcnt -> LDS tiles ready
        bf16x8 af[4], bfr[4];
        #pragma unroll
        for (int i = 0; i < 4; i++)
            af[i] = *(const bf16x8*)(As + (wr + i * 16 + l16) * 32 + quad * 8);
        #pragma unroll
        for (int j = 0; j < 4; j++)
            bfr[j] = *(const bf16x8*)(Bs + (wc + j * 16 + l16) * 32 + quad * 8);
        #pragma unroll
        for (int i = 0; i < 4; i++)
            #pragma unroll
            for (int j = 0; j < 4; j++)
                acc[i][j] = MFMA16(af[i], bfr[j], acc[i][j]);
    }

    float bv[4];
    #pragma unroll
    for (int j = 0; j < 4; j++) bv[j] = bias[n0 + wc + j * 16 + l16];

    // C/D layout: col = lane&15 (n), row = quad*4 + reg (m)
    #pragma unroll
    for (int i = 0; i < 4; i++) {
        #pragma unroll
        for (int j = 0; j < 4; j++) {
            int gn = n0 + wc + j * 16 + l16;
            #pragma unroll
            for (int r = 0; r < 4; r++) {
                int gm = m0 + wr + i * 16 + quad * 4 + r;
                float v = acc[i][j][r] + bv[j];
                size_t idx;
                if (LAYOUT == 2)      idx = (size_t)gm * 1024 + gn;
                else if (LAYOUT == 0) idx = (((size_t)(gm >> 11) * 16 + (gn >> 6)) * 2048 + (gm & 2047)) * 64 + (gn & 63);
                else                  idx = (((size_t)(gm >> 11) * 16 + (gn >> 6)) * 64 + (gn & 63)) * 2048 + (gm & 2047);
                if (OUTF32) ((float*)outv)[idx] = v;
                else        ((u16*)outv)[idx]   = f2bf(v);
            }
        }
    }
}

__global__ __launch_bounds__(256, 2)
void gemm_qkv(const u16* __restrict__ Qb, const u16* __restrict__ Kb, const u16* __restrict__ Vb,
              const u16* __restrict__ Wq, const u16* __restrict__ Wk, const u16* __restrict__ Wv,
              const float* __restrict__ bq, const float* __restrict__ bk, const float* __restrict__ bv,
              u16* __restrict__ qh, u16* __restrict__ kh, u16* __restrict__ vt)
{
    __shared__ __align__(16) u16 As[128 * 32];
    __shared__ __align__(16) u16 Bs[128 * 32];
    const int z = blockIdx.z;
    const u16* A = z == 0 ? Qb : (z == 1 ? Kb : Vb);
    const u16* W = z == 0 ? Wq : (z == 1 ? Wk : Wv);
    const float* bias = z == 0 ? bq : (z == 1 ? bk : bv);
    if (z < 2) gemm_body<0, 0>(A, W, bias, z == 0 ? qh : kh, As, Bs);
    else       gemm_body<1, 0>(A, W, bias, vt, As, Bs);
}

__global__ __launch_bounds__(256, 2)
void gemm_o(const u16* __restrict__ A, const u16* __restrict__ W,
            const float* __restrict__ bias, float* __restrict__ out)
{
    __shared__ __align__(16) u16 As[128 * 32];
    __shared__ __align__(16) u16 Bs[128 * 32];
    gemm_body<2, 1>(A, W, bias, out, As, Bs);
}

// ---------------------------------------------------------------------------
// Flash attention: block per (q-tile 128, head, batch); 4 waves x 32 q-rows.
// Padded LDS pitches (72/136) -> 2-way bank aliasing only (free).
// ---------------------------------------------------------------------------
#define KP 72
#define VP 136
#define PP 136

__global__ __launch_bounds__(256, 2)
void attn_fused(const u16* __restrict__ qh, const u16* __restrict__ kh,
                const u16* __restrict__ vt, u16* __restrict__ out)
{
    __shared__ __align__(16) u16 Ks[128 * KP];       // 18.4KB
    __shared__ __align__(16) u16 Vs[64 * VP];        // 17.4KB
    __shared__ __align__(16) u16 Ps[4 * 32 * PP];    // 34.8KB per-wave P scratch

    const int tid  = threadIdx.x;
    const int wave = tid >> 6, lane = tid & 63;
    const int quad = lane >> 4, l16 = lane & 15;
    const int q0 = blockIdx.x * 128;
    const int h = blockIdx.y, b = blockIdx.z;

    const size_t head = (size_t)(b * 16 + h);
    const u16* qh_h = qh + head * (2048 * 64);
    const u16* kh_h = kh + head * (2048 * 64);
    const u16* vt_h = vt + head * (64 * 2048);
    u16* pw = Ps + wave * (32 * PP);

    bf16x8 qf[2][2];   // A-op: m=lane&15, k=quad*8+j
    #pragma unroll
    for (int i = 0; i < 2; i++)
        #pragma unroll
        for (int ks = 0; ks < 2; ks++)
            qf[i][ks] = *(const bf16x8*)(qh_h + (size_t)(q0 + wave * 32 + i * 16 + l16) * 64 + ks * 32 + quad * 8);

    f32x4 oacc[2][4] = {};
    float m_s[2][4], l_s[2][4];
    #pragma unroll
    for (int i = 0; i < 2; i++)
        #pragma unroll
        for (int r = 0; r < 4; r++) { m_s[i][r] = -1e30f; l_s[i][r] = 0.0f; }

    const float c = 0.18033688011112042f;  // log2(e)/sqrt(64)

    for (int kt = 0; kt < 16; kt++) {
        const int kv0 = kt * 128;
        __syncthreads();  // prior iteration's Ks/Vs readers done
        #pragma unroll
        for (int it = 0; it < 4; it++) {
            int idx = it * 256 + tid;
            int kr = idx >> 3, kc = (idx & 7) * 8;
            *(short8*)(Ks + kr * KP + kc) = *(const short8*)(kh_h + (size_t)(kv0 + kr) * 64 + kc);
            int vr = idx >> 4, vc = (idx & 15) * 8;
            *(short8*)(Vs + vr * VP + vc) = *(const short8*)(vt_h + (size_t)vr * 2048 + kv0 + vc);
        }
        __syncthreads();

        // S = q.k^T
        f32x4 sacc[2][8] = {};
        #pragma unroll
        for (int j = 0; j < 8; j++) {
            #pragma unroll
            for (int ks = 0; ks < 2; ks++) {
                bf16x8 kf = *(const bf16x8*)(Ks + (j * 16 + l16) * KP + ks * 32 + quad * 8);
                #pragma unroll
                for (int i = 0; i < 2; i++)
                    sacc[i][j] = MFMA16(qf[i][ks], kf, sacc[i][j]);
            }
        }

        // Online softmax; row (i*16+quad*4+rg) lives in a 16-lane group
        #pragma unroll
        for (int i = 0; i < 2; i++) {
            #pragma unroll
            for (int rg = 0; rg < 4; rg++) {
                float mx = sacc[i][0][rg];
                #pragma unroll
                for (int j = 1; j < 8; j++) mx = fmaxf(mx, sacc[i][j][rg]);
                #pragma unroll
                for (int off = 8; off > 0; off >>= 1) mx = fmaxf(mx, __shfl_xor(mx, off));
                float mnew  = fmaxf(m_s[i][rg], mx);
                float alpha = __builtin_amdgcn_exp2f((m_s[i][rg] - mnew) * c);
                m_s[i][rg]  = mnew;
                float rs = 0.0f;
                #pragma unroll
                for (int j = 0; j < 8; j++) {
                    float p = __builtin_amdgcn_exp2f((sacc[i][j][rg] - mnew) * c);
                    rs += p;
                    pw[(i * 16 + quad * 4 + rg) * PP + j * 16 + l16] = f2bf(p);
                }
                #pragma unroll
                for (int off = 8; off > 0; off >>= 1) rs += __shfl_xor(rs, off);
                l_s[i][rg] = l_s[i][rg] * alpha + rs;
                #pragma unroll
                for (int dt = 0; dt < 4; dt++) oacc[i][dt][rg] *= alpha;
            }
        }
        // Ps is wave-private: wave-local LDS drain is sufficient (no barrier)
        asm volatile("s_waitcnt lgkmcnt(0)" ::: "memory");

        // O += P * V
        #pragma unroll
        for (int ks = 0; ks < 4; ks++) {
            #pragma unroll
            for (int i = 0; i < 2; i++) {
                bf16x8 pa = *(const bf16x8*)(pw + (i * 16 + l16) * PP + ks * 32 + quad * 8);
                #pragma unroll
                for (int dt = 0; dt < 4; dt++) {
                    bf16x8 vf = *(const bf16x8*)(Vs + (dt * 16 + l16) * VP + ks * 32 + quad * 8);
                    oacc[i][dt] = MFMA16(pa, vf, oacc[i][dt]);
                }
            }
        }
    }

    #pragma unroll
    for (int i = 0; i < 2; i++) {
        #pragma unroll
        for (int rg = 0; rg < 4; rg++) {
            float inv = 1.0f / l_s[i][rg];
            int gq = q0 + wave * 32 + i * 16 + quad * 4 + rg;
            #pragma unroll
            for (int dt = 0; dt < 4; dt++) {
                int col = h * 64 + dt * 16 + l16;
                out[((size_t)(b * 2048 + gq)) * 1024 + col] = f2bf(oacc[i][dt][rg] * inv);
            }
        }
    }
}

extern "C" void kernel_launch(void* const* d_in, const int* in_sizes, int n_in,
                              void* d_out, int out_size, void* d_ws, size_t ws_size,
                              hipStream_t stream)
{
    const float* Q   = (const float*)d_in[0];
    const float* Kin = (const float*)d_in[1];
    const float* V   = (const float*)d_in[2];
    const float* Wq  = (const float*)d_in[3];
    const float* bq  = (const float*)d_in[4];
    const float* Wk  = (const float*)d_in[5];
    const float* bk  = (const float*)d_in[6];
    const float* Wv  = (const float*)d_in[7];
    const float* bv  = (const float*)d_in[8];
    const float* Wo  = (const float*)d_in[9];
    const float* bo  = (const float*)d_in[10];

    const size_t TS = (size_t)2 * 2048 * 1024;   // 4.19M elem per activation buffer
    const size_t WS = (size_t)1024 * 1024;       // 1.05M elem per weight buffer
    u16* Qb  = (u16*)d_ws;
    u16* Kb  = Qb + TS;
    u16* Vb  = Kb + TS;
    u16* qh  = Vb + TS;
    u16* kh  = qh + TS;
    u16* vt  = kh + TS;
    u16* Wqb = vt + TS;
    u16* Wkb = Wqb + WS;
    u16* Wvb = Wkb + WS;
    u16* Wob = Wvb + WS;
    u16* at  = Qb;   // Qb dead after gemm_qkv

    cvt_qkv<<<dim3(2048, 3), 256, 0, stream>>>(Q, Kin, V, Qb, Kb, Vb);
    cvt_w  <<<dim3(512, 4),  256, 0, stream>>>(Wq, Wk, Wv, Wo, Wqb, Wkb, Wvb, Wob);
    gemm_qkv<<<dim3(8, 32, 3), 256, 0, stream>>>(Qb, Kb, Vb, Wqb, Wkb, Wvb, bq, bk, bv, qh, kh, vt);
    attn_fused<<<dim3(16, 16, 2), 256, 0, stream>>>(qh, kh, vt, at);
    gemm_o<<<dim3(8, 32), 256, 0, stream>>>(at, Wob, bo, (float*)d_out);
}